// Round 3
// baseline (536.946 us; speedup 1.0000x reference)
//
#include <hip/hip_runtime.h>
#include <hip/hip_cooperative_groups.h>

namespace cg = cooperative_groups;

// MultiboxLoss anchor matching: B=64, T=100, A=8732, NUM_CLASSES=21
// out = [loc (B,A,4) f32][conf (B,A) as f32]
// Round 7: fusion. R4-R6 showed a constant ~57us of non-phaseA time (3
// launches + atomicMax drain + k_encode cold start) vs <5us of actual
// encode work. Fuse init+phaseA+encode into ONE cooperative kernel:
//  - per-chunk per-t winners as plain agent-scope release stores (no
//    k_init, no global atomicMax tail)
//  - per-anchor results stay in regs/LDS across grid.sync (pa array gone)
//  - encode reduces the 18 chunk-partials per (b,t) and writes out, with
//    sh_box still warm in LDS. Numerics identical to R6 (Markstein IoU div;
//    IEEE div + logf in encode).
// Co-residency: 1152 blocks x 256thr; __launch_bounds__(256,8) caps VGPR
// at 64 => 8 blocks/CU allowed >= 4.5 needed. LDS ~10KB.
//   ws: [0, 921600): u64 keys2[B][T][NCHUNK] — per-chunk (iou_bits<<32)|~anchor
#define BB 64
#define TT 100
#define AA 8732
#define CHUNK 512                         // anchors per block (256 threads x 2)
#define NCHUNK ((AA + CHUNK - 1) / CHUNK) // 18

typedef unsigned long long u64;
typedef unsigned int u32;
typedef unsigned short u16;

// Faithful (<=1ulp) f32 division, 5 VALU, no VCC. Inputs always normal
// (u >= 4e-4); i == 0 returns exactly 0. Markstein remainder correction.
__device__ __forceinline__ float fdiv_faithful(float i, float u) {
    float r = __builtin_amdgcn_rcpf(u);                     // v_rcp_f32
    r = __builtin_fmaf(__builtin_fmaf(-u, r, 1.0f), r, r);  // Newton
    float q = __fmul_rn(i, r);
    float rem = __builtin_fmaf(-u, q, i);                   // exact remainder
    return __builtin_fmaf(rem, r, q);
}

// Bit-matching (vs numpy f32) intersection/union: _rn blocks fp-contract.
__device__ __forceinline__ float iou_f(float bx1, float by1, float bx2, float by2, float areab,
                                       float ax1, float ay1, float ax2, float ay2, float areaa) {
    float dx = fmaxf(__fsub_rn(fminf(bx2, ax2), fmaxf(bx1, ax1)), 0.0f);
    float dy = fmaxf(__fsub_rn(fminf(by2, ay2), fmaxf(by1, ay1)), 0.0f);
    float inter = __fmul_rn(dx, dy);
    float uni = __fsub_rn(__fadd_rn(areab, areaa), inter);
    return fdiv_faithful(inter, uni);
}

// 4 interleaved wave64 max reductions via DPP; lane 63 holds the wave max.
__device__ __forceinline__ void wave_max63_x4(float& x0, float& x1, float& x2, float& x3) {
#define DPP4(ctrl)                                                                              \
    {                                                                                           \
        int t0 = __builtin_amdgcn_update_dpp(__float_as_int(x0), __float_as_int(x0), (ctrl), 0xf, 0xf, false); \
        int t1 = __builtin_amdgcn_update_dpp(__float_as_int(x1), __float_as_int(x1), (ctrl), 0xf, 0xf, false); \
        int t2 = __builtin_amdgcn_update_dpp(__float_as_int(x2), __float_as_int(x2), (ctrl), 0xf, 0xf, false); \
        int t3 = __builtin_amdgcn_update_dpp(__float_as_int(x3), __float_as_int(x3), (ctrl), 0xf, 0xf, false); \
        x0 = fmaxf(x0, __int_as_float(t0));                                                     \
        x1 = fmaxf(x1, __int_as_float(t1));                                                     \
        x2 = fmaxf(x2, __int_as_float(t2));                                                     \
        x3 = fmaxf(x3, __int_as_float(t3));                                                     \
    }
    DPP4(0x111)  // row_shr:1
    DPP4(0x112)  // row_shr:2
    DPP4(0x114)  // row_shr:4
    DPP4(0x118)  // row_shr:8   -> lane15 of each row16 = row max
    DPP4(0x142)  // row_bcast:15
    DPP4(0x143)  // row_bcast:31 -> lane63 = wave max
#undef DPP4
}

__global__ __launch_bounds__(256, 8) void k_fused(const float* __restrict__ targets,
                                                  const float* __restrict__ anchors,
                                                  u64* __restrict__ keys2,
                                                  float* __restrict__ out) {
    const int b = blockIdx.y;
    const int chunk = blockIdx.x;
    const int tid = threadIdx.x;
    const int a0 = chunk * CHUNK + tid * 2;   // AA even => pair never straddles
    const bool valid = a0 < AA;
    const int lane = tid & 63, wv = tid >> 6; // wv 0..3

    __shared__ float4 sh_box[TT];                 // x1,y1,x2,y2
    __shared__ __align__(16) float sh_area[TT];   // precomputed box area
    __shared__ float sh_lab[TT];                  // label
    __shared__ u64 sh_red[4][TT];                 // [wave][t] per-target winners
    __shared__ u32 sh_f[256];                     // per-thread packed 2x u16 (gi|pos<<7)
    __shared__ u32 sh_ov[CHUNK];                  // override map (local anchor -> 0x100|t)

    if (tid < TT) {
        const float* tg = targets + ((size_t)b * TT + tid) * 5;
        float x1 = tg[0], y1 = tg[1], x2 = tg[2], y2 = tg[3];
        sh_box[tid] = make_float4(x1, y1, x2, y2);
        sh_area[tid] = __fmul_rn(__fsub_rn(x2, x1), __fsub_rn(y2, y1));
        sh_lab[tid] = tg[4];
    }
    __syncthreads();

    // Anchor point-form. OOB lanes use dummy (0,0,0,0,area=1): intersection
    // is exactly 0 => IoU = 0 exactly; ties at larger index never win.
    float ax10 = 0.f, ay10 = 0.f, ax20 = 0.f, ay20 = 0.f, aa0 = 1.f;
    float ax11 = 0.f, ay11 = 0.f, ax21 = 0.f, ay21 = 0.f, aa1 = 1.f;
    if (valid) {
        const float4* anc = (const float4*)(anchors + (size_t)a0 * 4);
        float4 c0 = anc[0], c1 = anc[1];
        float hx0 = __fmul_rn(c0.z, 0.5f), hy0 = __fmul_rn(c0.w, 0.5f);
        ax10 = __fsub_rn(c0.x, hx0); ay10 = __fsub_rn(c0.y, hy0);
        ax20 = __fadd_rn(c0.x, hx0); ay20 = __fadd_rn(c0.y, hy0);
        aa0 = __fmul_rn(__fsub_rn(ax20, ax10), __fsub_rn(ay20, ay10));
        float hx1 = __fmul_rn(c1.z, 0.5f), hy1 = __fmul_rn(c1.w, 0.5f);
        ax11 = __fsub_rn(c1.x, hx1); ay11 = __fsub_rn(c1.y, hy1);
        ax21 = __fadd_rn(c1.x, hx1); ay21 = __fadd_rn(c1.y, hy1);
        aa1 = __fmul_rn(__fsub_rn(ax21, ax11), __fsub_rn(ay21, ay11));
    }

    float best0 = -1.f, best1 = -1.f;   // iou >= 0 > -1: replaced on first t
    int gi0 = 0, gi1 = 0;
    const u32 wave_base = (u32)chunk * CHUNK + (u32)wv * 128u;

    for (int t = 0; t < TT; t += 4) {
        float4 B0 = sh_box[t + 0], B1 = sh_box[t + 1];
        float4 B2 = sh_box[t + 2], B3 = sh_box[t + 3];
        const float4 arv = *(const float4*)&sh_area[t];   // t%4==0 => aligned
        float ar0 = arv.x, ar1 = arv.y, ar2 = arv.z, ar3 = arv.w;

        // 8 independent IoUs: Markstein divs pipeline freely (no VCC)
        float v00 = iou_f(B0.x, B0.y, B0.z, B0.w, ar0, ax10, ay10, ax20, ay20, aa0);
        float v01 = iou_f(B0.x, B0.y, B0.z, B0.w, ar0, ax11, ay11, ax21, ay21, aa1);
        float v10 = iou_f(B1.x, B1.y, B1.z, B1.w, ar1, ax10, ay10, ax20, ay20, aa0);
        float v11 = iou_f(B1.x, B1.y, B1.z, B1.w, ar1, ax11, ay11, ax21, ay21, aa1);
        float v20 = iou_f(B2.x, B2.y, B2.z, B2.w, ar2, ax10, ay10, ax20, ay20, aa0);
        float v21 = iou_f(B2.x, B2.y, B2.z, B2.w, ar2, ax11, ay11, ax21, ay21, aa1);
        float v30 = iou_f(B3.x, B3.y, B3.z, B3.w, ar3, ax10, ay10, ax20, ay20, aa0);
        float v31 = iou_f(B3.x, B3.y, B3.z, B3.w, ar3, ax11, ay11, ax21, ay21, aa1);

        // per-anchor argmax over t: ascending t, strict > => first-t-wins
        if (v00 > best0) { best0 = v00; gi0 = t; }
        if (v10 > best0) { best0 = v10; gi0 = t + 1; }
        if (v20 > best0) { best0 = v20; gi0 = t + 2; }
        if (v30 > best0) { best0 = v30; gi0 = t + 3; }
        if (v01 > best1) { best1 = v01; gi1 = t; }
        if (v11 > best1) { best1 = v11; gi1 = t + 1; }
        if (v21 > best1) { best1 = v21; gi1 = t + 2; }
        if (v31 > best1) { best1 = v31; gi1 = t + 3; }

        // per-t argmax over this wave's 128 anchors
        float vm0 = fmaxf(v00, v01), vm1 = fmaxf(v10, v11);
        float vm2 = fmaxf(v20, v21), vm3 = fmaxf(v30, v31);
        float w0 = vm0, w1 = vm1, w2 = vm2, w3 = vm3;
        wave_max63_x4(w0, w1, w2, w3);
        u32 wm0 = (u32)__builtin_amdgcn_readlane(__float_as_int(w0), 63);
        u32 wm1 = (u32)__builtin_amdgcn_readlane(__float_as_int(w1), 63);
        u32 wm2 = (u32)__builtin_amdgcn_readlane(__float_as_int(w2), 63);
        u32 wm3 = (u32)__builtin_amdgcn_readlane(__float_as_int(w3), 63);
        u64 me0 = __ballot(vm0 == __uint_as_float(wm0));
        u64 mp0 = __ballot(v01 > v00);
        u64 me1 = __ballot(vm1 == __uint_as_float(wm1));
        u64 mp1 = __ballot(v11 > v10);
        u64 me2 = __ballot(vm2 == __uint_as_float(wm2));
        u64 mp2 = __ballot(v21 > v20);
        u64 me3 = __ballot(vm3 == __uint_as_float(wm3));
        u64 mp3 = __ballot(v31 > v30);
        u32 wl0 = (u32)(__ffsll((long long)me0) - 1);
        u32 wl1 = (u32)(__ffsll((long long)me1) - 1);
        u32 wl2 = (u32)(__ffsll((long long)me2) - 1);
        u32 wl3 = (u32)(__ffsll((long long)me3) - 1);
        u32 g0 = wave_base + wl0 * 2u + (u32)((mp0 >> wl0) & 1ULL);
        u32 g1 = wave_base + wl1 * 2u + (u32)((mp1 >> wl1) & 1ULL);
        u32 g2 = wave_base + wl2 * 2u + (u32)((mp2 >> wl2) & 1ULL);
        u32 g3 = wave_base + wl3 * 2u + (u32)((mp3 >> wl3) & 1ULL);
        if (lane == 0) {
            u64* r = &sh_red[wv][t];
            r[0] = (((u64)wm0) << 32) | (u32)~g0;
            r[1] = (((u64)wm1) << 32) | (u32)~g1;
            r[2] = (((u64)wm2) << 32) | (u32)~g2;
            r[3] = (((u64)wm3) << 32) | (u32)~g3;
        }
    }

    // pack per-anchor result for the encode phase (regs -> LDS, no global pa)
    {
        u32 f0 = (u32)gi0 | (best0 >= 0.5f ? 0x80u : 0u);
        u32 f1 = (u32)gi1 | (best1 >= 0.5f ? 0x80u : 0u);
        sh_f[tid] = f0 | (f1 << 16);
    }
    __syncthreads();   // sh_red complete

    if (tid < TT) {
        u64 m0 = sh_red[0][tid], m1 = sh_red[1][tid];
        u64 m2 = sh_red[2][tid], m3 = sh_red[3][tid];
        u64 m = m0 > m1 ? m0 : m1;
        if (m2 > m) m = m2;
        if (m3 > m) m = m3;
        // per-chunk partial winner: plain (release, agent-scope) store —
        // cross-XCD visibility for the post-sync reduction.
        __hip_atomic_store(&keys2[((size_t)b * TT + tid) * NCHUNK + chunk], m,
                           __ATOMIC_RELEASE, __HIP_MEMORY_SCOPE_AGENT);
    }

    cg::this_grid().sync();

    // ---------------- encode phase ----------------
    sh_ov[tid] = 0;
    sh_ov[tid + 256] = 0;
    __syncthreads();

    if (tid < TT) {
        const u64* kp = &keys2[((size_t)b * TT + tid) * NCHUNK];
        u64 m = __hip_atomic_load(&kp[0], __ATOMIC_ACQUIRE, __HIP_MEMORY_SCOPE_AGENT);
        for (int c = 1; c < NCHUNK; ++c) {
            u64 v = __hip_atomic_load(&kp[c], __ATOMIC_ACQUIRE, __HIP_MEMORY_SCOPE_AGENT);
            if (v > m) m = v;   // strict >: ties keep earlier; ~g in low bits
        }                       // already favors smaller anchor on value tie
        u32 g = ~(u32)m;        // global winner anchor for target tid
        int loc = (int)g - chunk * CHUNK;
        if (loc >= 0 && loc < CHUNK)
            atomicMax(&sh_ov[loc], 0x100u | (u32)tid);   // max t = last-wins
    }
    __syncthreads();

    #pragma unroll
    for (int k = 0; k < 2; ++k) {
        const int idx = tid + k * 256;
        const int a = chunk * CHUNK + idx;
        if (a < AA) {
            u32 ov = sh_ov[idx];
            u16 fv = ((const u16*)sh_f)[idx];
            int gi; bool pos;
            if (ov) { gi = (int)(ov & 0x7F); pos = true; }
            else     { gi = (int)(fv & 0x7F); pos = (fv & 0x80) != 0; }

            const float4 anc = *(const float4*)(anchors + (size_t)a * 4);
            const float4 Bx = sh_box[gi];
            const float cx = (Bx.x + Bx.z) * 0.5f, cy = (Bx.y + Bx.w) * 0.5f;
            const float w = Bx.z - Bx.x, h = Bx.w - Bx.y;
            const float l0 = (cx - anc.x) / (0.1f * anc.z);
            const float l1 = (cy - anc.y) / (0.1f * anc.w);
            const float l2 = logf(w / anc.z) / 0.2f;
            const float l3 = logf(h / anc.w) / 0.2f;

            const size_t base = ((size_t)b * AA + a) * 4;
            *(float4*)(out + base) = make_float4(l0, l1, l2, l3);
            float conf = pos ? (float)(int)(sh_lab[gi] + 1.0f) : 0.0f;
            out[(size_t)BB * AA * 4 + (size_t)b * AA + a] = conf;
        }
    }
}

extern "C" void kernel_launch(void* const* d_in, const int* in_sizes, int n_in,
                              void* d_out, int out_size, void* d_ws, size_t ws_size,
                              hipStream_t stream) {
    const float* targets = (const float*)d_in[0];  // (B,T,5)
    const float* anchors = (const float*)d_in[1];  // (A,4)
    float* out = (float*)d_out;
    u64* keys2 = (u64*)d_ws;                       // B*T*NCHUNK*8 = 921.6 KB

    dim3 grid(NCHUNK, BB), block(256);
    void* args[] = {(void*)&targets, (void*)&anchors, (void*)&keys2, (void*)&out};
    hipLaunchCooperativeKernel((const void*)k_fused, grid, block, args, 0, stream);
}

// Round 4
// 123.229 us; speedup vs baseline: 4.3573x; 4.3573x over previous
//
#include <hip/hip_runtime.h>

// MultiboxLoss anchor matching: B=64, T=100, A=8732, NUM_CLASSES=21
// out = [loc (B,A,4) f32][conf (B,A) as f32]
// Round 8: packed f32. R7 (cooperative fusion) regressed 4x: grid.sync +
// agent-scope fences across 8 non-coherent XCD L2s cost ~400us; AND the
// total-minus-kernel gap (~55-66us) is FIXED harness overhead, identical
// for 1 vs 3 launches -> launch fusion is a dead end. Reverted to R6
// structure. This round: the 2 anchors/thread become float2 halves; the
// IoU subs/mul/union/Markstein-div lower to v_pk_{add,mul,fma}_f32
// (gfx90a+ packed fp32, selected from <2 x float> IR). Per-t anchor-pair
// IoU: 32 -> 23 issue slots (~16% of the loop). min/max stay scalar (no
// pk_min/max_f32 on CDNA). fp-contract off in iou => bit-identical to R6.
//   ws: [0, 51200): u64 keys[B*T]        — (iou_bits<<32)|~anchor, atomicMax
//       [51200, +B*A*2): u16 pa[B*A]     — per-anchor (gi | pos<<7)
#define BB 64
#define TT 100
#define TSPLIT 52                         // half0: [0,52) 13 iters, half1: [52,100) 12 iters
#define AA 8732
#define CHUNK 512                         // anchors per block (256 thr-pairs x 2)
#define NCHUNK ((AA + CHUNK - 1) / CHUNK) // 18

typedef unsigned long long u64;
typedef unsigned int u32;
typedef unsigned short u16;
typedef float v2f __attribute__((ext_vector_type(2)));

// Packed IoU for an anchor PAIR vs one box. Geometric min/max/clamp are
// scalar (no v_pk_min/max_f32); sub/mul/add and the faithful Markstein
// division pack 2-for-1 into v_pk_* VOP3P. All ops IEEE-RN per half =>
// bit-identical to the scalar version. fp contract off: no mul+sub fusion
// (explicit elementwise_fma still emits fma).
__device__ __forceinline__ v2f pk_iou(float bx1, float by1, float bx2, float by2, float areab,
                                      v2f ax1, v2f ay1, v2f ax2, v2f ay2, v2f areaa) {
#pragma clang fp contract(off)
    v2f bx1v = {bx1, bx1}, by1v = {by1, by1}, bx2v = {bx2, bx2}, by2v = {by2, by2};
    v2f tlx = __builtin_elementwise_max(bx1v, ax1);
    v2f tly = __builtin_elementwise_max(by1v, ay1);
    v2f brx = __builtin_elementwise_min(bx2v, ax2);
    v2f bry = __builtin_elementwise_min(by2v, ay2);
    v2f zero = {0.f, 0.f};
    v2f dx = __builtin_elementwise_max(brx - tlx, zero);   // pk_add(neg) + max
    v2f dy = __builtin_elementwise_max(bry - tly, zero);
    v2f inter = dx * dy;                                   // pk_mul (multi-use: no contract)
    v2f arv = {areab, areab};
    v2f uni = (arv + areaa) - inter;                       // pk_add, pk_add(neg)
    // faithful (<=1ulp) div, no VCC: rcp + Newton + fma remainder correction
    v2f r = {__builtin_amdgcn_rcpf(uni.x), __builtin_amdgcn_rcpf(uni.y)};
    v2f one = {1.f, 1.f};
    r = __builtin_elementwise_fma(__builtin_elementwise_fma(-uni, r, one), r, r);
    v2f q = inter * r;                                     // pk_mul
    v2f rem = __builtin_elementwise_fma(-uni, q, inter);   // exact remainder
    return __builtin_elementwise_fma(rem, r, q);
}

// 4 interleaved wave64 max reductions via DPP; lane 63 holds the wave max.
__device__ __forceinline__ void wave_max63_x4(float& x0, float& x1, float& x2, float& x3) {
#define DPP4(ctrl)                                                                              \
    {                                                                                           \
        int t0 = __builtin_amdgcn_update_dpp(__float_as_int(x0), __float_as_int(x0), (ctrl), 0xf, 0xf, false); \
        int t1 = __builtin_amdgcn_update_dpp(__float_as_int(x1), __float_as_int(x1), (ctrl), 0xf, 0xf, false); \
        int t2 = __builtin_amdgcn_update_dpp(__float_as_int(x2), __float_as_int(x2), (ctrl), 0xf, 0xf, false); \
        int t3 = __builtin_amdgcn_update_dpp(__float_as_int(x3), __float_as_int(x3), (ctrl), 0xf, 0xf, false); \
        x0 = fmaxf(x0, __int_as_float(t0));                                                     \
        x1 = fmaxf(x1, __int_as_float(t1));                                                     \
        x2 = fmaxf(x2, __int_as_float(t2));                                                     \
        x3 = fmaxf(x3, __int_as_float(t3));                                                     \
    }
    DPP4(0x111)  // row_shr:1
    DPP4(0x112)  // row_shr:2
    DPP4(0x114)  // row_shr:4
    DPP4(0x118)  // row_shr:8   -> lane15 of each row16 = row max
    DPP4(0x142)  // row_bcast:15
    DPP4(0x143)  // row_bcast:31 -> lane63 = wave max
#undef DPP4
}

__global__ __launch_bounds__(256) void k_init(u64* __restrict__ keys) {
    int i = blockIdx.x * 256 + threadIdx.x;
    if (i < BB * TT) keys[i] = 0ULL;
}

// Fused pass: block = (b, 512-anchor chunk), 512 threads = 8 waves.
// Waves 0-3 cover t in [0,52), waves 4-7 cover [52,100) over the SAME
// 512 anchors (2/thread, packed as float2 halves). t-unroll x4.
__global__ __launch_bounds__(512) void k_phaseA(const float* __restrict__ targets,
                                                const float* __restrict__ anchors,
                                                u64* __restrict__ keys,
                                                u16* __restrict__ pa) {
    const int b = blockIdx.y;
    const int tid = threadIdx.x;
    const int half = tid >> 8;            // 0: t<52, 1: t>=52
    const int u = tid & 255;              // pair index within chunk
    const int a0 = blockIdx.x * CHUNK + u * 2;  // AA even => pair never straddles
    const bool valid = a0 < AA;
    const int lane = tid & 63, wv = tid >> 6;   // wv 0..7; (wv&3) = lane-group within half

    __shared__ float4 sh_box[TT];                 // x1,y1,x2,y2
    __shared__ __align__(16) float sh_area[TT];   // precomputed box area
    __shared__ u64 sh_red[4][TT];                 // [wave-group][t] per-target winners
    __shared__ u64 sh_pa[CHUNK];                  // per-anchor half-0 results for merge

    if (tid < TT) {
        const float* tg = targets + ((size_t)b * TT + tid) * 5;
        float x1 = tg[0], y1 = tg[1], x2 = tg[2], y2 = tg[3];
        sh_box[tid] = make_float4(x1, y1, x2, y2);
        sh_area[tid] = __fmul_rn(__fsub_rn(x2, x1), __fsub_rn(y2, y1));
    }
    __syncthreads();

    // Anchor point-form, packed: half .x = anchor a0, half .y = anchor a0+1.
    // OOB lanes use dummy (0,0,0,0,area=1): intersection is exactly 0 =>
    // IoU = 0/(areab+1) = 0 exactly; ties at larger index never win.
    v2f ax1 = {0.f, 0.f}, ay1 = {0.f, 0.f}, ax2 = {0.f, 0.f}, ay2 = {0.f, 0.f};
    v2f aarea = {1.f, 1.f};
    if (valid) {
        const float4* anc = (const float4*)(anchors + (size_t)a0 * 4);
        float4 c0 = anc[0], c1 = anc[1];
        float hx0 = __fmul_rn(c0.z, 0.5f), hy0 = __fmul_rn(c0.w, 0.5f);
        float hx1 = __fmul_rn(c1.z, 0.5f), hy1 = __fmul_rn(c1.w, 0.5f);
        ax1 = (v2f){__fsub_rn(c0.x, hx0), __fsub_rn(c1.x, hx1)};
        ay1 = (v2f){__fsub_rn(c0.y, hy0), __fsub_rn(c1.y, hy1)};
        ax2 = (v2f){__fadd_rn(c0.x, hx0), __fadd_rn(c1.x, hx1)};
        ay2 = (v2f){__fadd_rn(c0.y, hy0), __fadd_rn(c1.y, hy1)};
        aarea = (v2f){__fmul_rn(__fsub_rn(ax2.x, ax1.x), __fsub_rn(ay2.x, ay1.x)),
                      __fmul_rn(__fsub_rn(ax2.y, ax1.y), __fsub_rn(ay2.y, ay1.y))};
    }

    float best0 = -1.f, best1 = -1.f;     // iou >= 0 > -1: always replaced on first t
    int gi0 = 0, gi1 = 0;
    const u32 wave_base = (u32)blockIdx.x * CHUNK + (u32)(wv & 3) * 128u;

    const int tbeg = half ? TSPLIT : 0;
    const int tend = half ? TT : TSPLIT;
    for (int t = tbeg; t < tend; t += 4) {
        // 4 boxes + areas: reads batch under one lgkm wait; broadcast (conflict-free)
        float4 B0 = sh_box[t + 0], B1 = sh_box[t + 1];
        float4 B2 = sh_box[t + 2], B3 = sh_box[t + 3];
        const float4 arv = *(const float4*)&sh_area[t];   // t%4==0 => 16B aligned
        float ar0 = arv.x, ar1 = arv.y, ar2 = arv.z, ar3 = arv.w;

        // 4 packed IoU pairs (= 8 IoUs): v_pk math, divs pipeline (no VCC)
        v2f v0 = pk_iou(B0.x, B0.y, B0.z, B0.w, ar0, ax1, ay1, ax2, ay2, aarea);
        v2f v1 = pk_iou(B1.x, B1.y, B1.z, B1.w, ar1, ax1, ay1, ax2, ay2, aarea);
        v2f v2 = pk_iou(B2.x, B2.y, B2.z, B2.w, ar2, ax1, ay1, ax2, ay2, aarea);
        v2f v3 = pk_iou(B3.x, B3.y, B3.z, B3.w, ar3, ax1, ay1, ax2, ay2, aarea);
        float v00 = v0.x, v01 = v0.y;
        float v10 = v1.x, v11 = v1.y;
        float v20 = v2.x, v21 = v2.y;
        float v30 = v3.x, v31 = v3.y;

        // per-anchor argmax over t: ascending t, strict > => first-t-wins
        if (v00 > best0) { best0 = v00; gi0 = t; }
        if (v10 > best0) { best0 = v10; gi0 = t + 1; }
        if (v20 > best0) { best0 = v20; gi0 = t + 2; }
        if (v30 > best0) { best0 = v30; gi0 = t + 3; }
        if (v01 > best1) { best1 = v01; gi1 = t; }
        if (v11 > best1) { best1 = v11; gi1 = t + 1; }
        if (v21 > best1) { best1 = v21; gi1 = t + 2; }
        if (v31 > best1) { best1 = v31; gi1 = t + 3; }

        // per-t argmax over this wave's 128 anchors
        float vm0 = fmaxf(v00, v01), vm1 = fmaxf(v10, v11);
        float vm2 = fmaxf(v20, v21), vm3 = fmaxf(v30, v31);
        float w0 = vm0, w1 = vm1, w2 = vm2, w3 = vm3;
        wave_max63_x4(w0, w1, w2, w3);
        u32 wm0 = (u32)__builtin_amdgcn_readlane(__float_as_int(w0), 63);
        u32 wm1 = (u32)__builtin_amdgcn_readlane(__float_as_int(w1), 63);
        u32 wm2 = (u32)__builtin_amdgcn_readlane(__float_as_int(w2), 63);
        u32 wm3 = (u32)__builtin_amdgcn_readlane(__float_as_int(w3), 63);
        // winner lane = smallest lane matching max (first-anchor-wins);
        // pair-bit from the v1>v0 ballot (strict >: first-index-wins in pair)
        u64 me0 = __ballot(vm0 == __uint_as_float(wm0));
        u64 mp0 = __ballot(v01 > v00);
        u64 me1 = __ballot(vm1 == __uint_as_float(wm1));
        u64 mp1 = __ballot(v11 > v10);
        u64 me2 = __ballot(vm2 == __uint_as_float(wm2));
        u64 mp2 = __ballot(v21 > v20);
        u64 me3 = __ballot(vm3 == __uint_as_float(wm3));
        u64 mp3 = __ballot(v31 > v30);
        u32 wl0 = (u32)(__ffsll((long long)me0) - 1);
        u32 wl1 = (u32)(__ffsll((long long)me1) - 1);
        u32 wl2 = (u32)(__ffsll((long long)me2) - 1);
        u32 wl3 = (u32)(__ffsll((long long)me3) - 1);
        u32 g0 = wave_base + wl0 * 2u + (u32)((mp0 >> wl0) & 1ULL);
        u32 g1 = wave_base + wl1 * 2u + (u32)((mp1 >> wl1) & 1ULL);
        u32 g2 = wave_base + wl2 * 2u + (u32)((mp2 >> wl2) & 1ULL);
        u32 g3 = wave_base + wl3 * 2u + (u32)((mp3 >> wl3) & 1ULL);
        if (lane == 0) {
            // [wv&3][t..t+3] contiguous => compiler can merge to b128 stores
            u64* r = &sh_red[wv & 3][t];
            r[0] = (((u64)wm0) << 32) | (u32)~g0;
            r[1] = (((u64)wm1) << 32) | (u32)~g1;
            r[2] = (((u64)wm2) << 32) | (u32)~g2;
            r[3] = (((u64)wm3) << 32) | (u32)~g3;
        }
    }
    __syncthreads();   // sh_red complete (each t written by exactly its half's 4 waves)

    if (tid < TT) {
        u64 m0 = sh_red[0][tid], m1 = sh_red[1][tid];
        u64 m2 = sh_red[2][tid], m3 = sh_red[3][tid];
        u64 m = m0 > m1 ? m0 : m1;
        if (m2 > m) m = m2;
        if (m3 > m) m = m3;
        atomicMax(&keys[b * TT + tid], m);
    }

    // Per-anchor merge across t-halves. Key = bits<<32 | ~gi: value-desc,
    // tie on value bits -> half0 auto-wins (~gi0 > ~gi1 since gi0 < 52 <= gi1).
    if (half == 0) {
        sh_pa[u * 2 + 0] = (((u64)__float_as_uint(best0)) << 32) | (u32)(~(u32)gi0);
        sh_pa[u * 2 + 1] = (((u64)__float_as_uint(best1)) << 32) | (u32)(~(u32)gi1);
    }
    __syncthreads();
    if (half == 1 && valid) {
        u64 k0 = (((u64)__float_as_uint(best0)) << 32) | (u32)(~(u32)gi0);
        u64 k1 = (((u64)__float_as_uint(best1)) << 32) | (u32)(~(u32)gi1);
        u64 m0 = sh_pa[u * 2 + 0]; if (k0 > m0) m0 = k0;
        u64 m1 = sh_pa[u * 2 + 1]; if (k1 > m1) m1 = k1;
        u32 gA0 = (~(u32)m0) & 0x7Fu;
        u32 gA1 = (~(u32)m1) & 0x7Fu;
        float bv0 = __uint_as_float((u32)(m0 >> 32));
        float bv1 = __uint_as_float((u32)(m1 >> 32));
        u32 f0 = gA0 | (bv0 >= 0.5f ? 0x80u : 0u);
        u32 f1 = gA1 | (bv1 >= 0.5f ? 0x80u : 0u);
        *(u32*)(pa + (size_t)b * AA + a0) = f0 | (f1 << 16);  // 4B-aligned
    }
}

// Encode: thread per (b,a). Override via LDS atomicMax scatter
// (value 0x100|t monotone in t => last-wins, matching .at[].set semantics).
__global__ __launch_bounds__(256) void k_encode(const float* __restrict__ targets,
                                                const float* __restrict__ anchors,
                                                const u64* __restrict__ keys,
                                                const u16* __restrict__ pa,
                                                float* __restrict__ out) {
    const int b = blockIdx.y;
    const int a = blockIdx.x * 256 + threadIdx.x;

    __shared__ float sh_t[TT][6];   // x1,y1,x2,y2,label
    __shared__ u32 sh_ov[256];

    sh_ov[threadIdx.x] = 0;
    __syncthreads();
    for (int t = threadIdx.x; t < TT; t += 256) {
        const float* tg = targets + ((size_t)b * TT + t) * 5;
        sh_t[t][0] = tg[0]; sh_t[t][1] = tg[1];
        sh_t[t][2] = tg[2]; sh_t[t][3] = tg[3];
        sh_t[t][4] = tg[4];
        u32 at = ~(u32)(keys[b * TT + t] & 0xFFFFFFFFu);
        if ((at >> 8) == (u32)blockIdx.x)
            atomicMax(&sh_ov[at & 255], 0x100u | (u32)t);
    }
    __syncthreads();
    if (a >= AA) return;

    u32 ov = sh_ov[threadIdx.x];
    u32 v = pa[(size_t)b * AA + a];
    int gi; bool pos;
    if (ov) { gi = (int)(ov & 0x7F); pos = true; }
    else     { gi = (int)(v & 0x7F); pos = (v & 0x80) != 0; }

    const float4 anc = *(const float4*)(anchors + (size_t)a * 4);
    const float mx1 = sh_t[gi][0], my1 = sh_t[gi][1], mx2 = sh_t[gi][2], my2 = sh_t[gi][3];
    const float cx = (mx1 + mx2) * 0.5f, cy = (my1 + my2) * 0.5f;
    const float w = mx2 - mx1, h = my2 - my1;
    const float l0 = (cx - anc.x) / (0.1f * anc.z);
    const float l1 = (cy - anc.y) / (0.1f * anc.w);
    const float l2 = logf(w / anc.z) / 0.2f;
    const float l3 = logf(h / anc.w) / 0.2f;

    const size_t base = ((size_t)b * AA + a) * 4;
    *(float4*)(out + base) = make_float4(l0, l1, l2, l3);
    float conf = pos ? (float)(int)(sh_t[gi][4] + 1.0f) : 0.0f;
    out[(size_t)BB * AA * 4 + (size_t)b * AA + a] = conf;
}

extern "C" void kernel_launch(void* const* d_in, const int* in_sizes, int n_in,
                              void* d_out, int out_size, void* d_ws, size_t ws_size,
                              hipStream_t stream) {
    const float* targets = (const float*)d_in[0];  // (B,T,5)
    const float* anchors = (const float*)d_in[1];  // (A,4)
    float* out = (float*)d_out;
    u64* keys = (u64*)d_ws;                                // 51.2 KB
    u16* pa = (u16*)((char*)d_ws + (size_t)BB * TT * 8);   // 1.09 MB

    k_init<<<(BB * TT + 255) / 256, 256, 0, stream>>>(keys);
    dim3 gA(NCHUNK, BB);
    k_phaseA<<<gA, 512, 0, stream>>>(targets, anchors, keys, pa);
    dim3 gE((AA + 255) / 256, BB);
    k_encode<<<gE, 256, 0, stream>>>(targets, anchors, keys, pa, out);
}

// Round 5
// 121.703 us; speedup vs baseline: 4.4119x; 1.0125x over previous
//
#include <hip/hip_runtime.h>

// MultiboxLoss anchor matching: B=64, T=100, A=8732, NUM_CLASSES=21
// out = [loc (B,A,4) f32][conf (B,A) as f32]
// Round 9: grid balance. R5/R6 ran 1152 blocks x 8 waves = 4 blocks/CU
// co-resident -> capacity 1024 -> round 1 full + round 2 = 128 blocks on
// 12.5% of the machine: time-avg utilization 56% == measured Occupancy
// ~52%. HALF of phaseA was dispatch tail. Fix: split t across gridDim.z=2
// (2304 blocks, 2.25 rounds, util 75%). Per-anchor results can't fully
// merge in-block anymore: each z-block plain-stores its u64 key
// (bits<<32|~gi) to pa2[b][a][z] ALIASED ONTO the out loc region (exactly
// 16B/anchor); k_encode reads its own cell, merges (max, tie->smaller gi
// = first-t, same as in-block merge), then overwrites it. No atomics, no
// extra workspace. R8's pk_iou reverted (neutral-negative). Numerics
// otherwise identical to R6 (Markstein IoU div).
//   ws: [0, 51200): u64 keys[B*T] — (iou_bits<<32)|~anchor, atomicMax
//   out loc region doubles as pa2[B][A][2] u64 scratch until k_encode.
#define BB 64
#define TT 100
#define AA 8732
#define CHUNK 512                         // anchors per block (256 thr-pairs x 2)
#define NCHUNK ((AA + CHUNK - 1) / CHUNK) // 18

typedef unsigned long long u64;
typedef unsigned int u32;
typedef unsigned short u16;

// t-range boundaries: [tbl[2z+half], tbl[2z+half+1]) per (z, in-block half).
// All multiples of 4 => clean 4-unroll, no tail code. z covers tbl[2z,2z+2).
__constant__ int c_tbl[5] = {0, 28, 52, 76, 100};

// Faithful (<=1ulp) f32 division, 5 VALU, no VCC. Inputs always normal
// (u >= 4e-4); i == 0 returns exactly 0. Markstein remainder correction.
__device__ __forceinline__ float fdiv_faithful(float i, float u) {
    float r = __builtin_amdgcn_rcpf(u);                     // v_rcp_f32
    r = __builtin_fmaf(__builtin_fmaf(-u, r, 1.0f), r, r);  // Newton
    float q = __fmul_rn(i, r);
    float rem = __builtin_fmaf(-u, q, i);                   // exact remainder
    return __builtin_fmaf(rem, r, q);
}

// Bit-matching (vs numpy f32) intersection/union: _rn blocks fp-contract.
__device__ __forceinline__ float iou_f(float bx1, float by1, float bx2, float by2, float areab,
                                       float ax1, float ay1, float ax2, float ay2, float areaa) {
    float dx = fmaxf(__fsub_rn(fminf(bx2, ax2), fmaxf(bx1, ax1)), 0.0f);
    float dy = fmaxf(__fsub_rn(fminf(by2, ay2), fmaxf(by1, ay1)), 0.0f);
    float inter = __fmul_rn(dx, dy);
    float uni = __fsub_rn(__fadd_rn(areab, areaa), inter);
    return fdiv_faithful(inter, uni);
}

// 4 interleaved wave64 max reductions via DPP; lane 63 holds the wave max.
__device__ __forceinline__ void wave_max63_x4(float& x0, float& x1, float& x2, float& x3) {
#define DPP4(ctrl)                                                                              \
    {                                                                                           \
        int t0 = __builtin_amdgcn_update_dpp(__float_as_int(x0), __float_as_int(x0), (ctrl), 0xf, 0xf, false); \
        int t1 = __builtin_amdgcn_update_dpp(__float_as_int(x1), __float_as_int(x1), (ctrl), 0xf, 0xf, false); \
        int t2 = __builtin_amdgcn_update_dpp(__float_as_int(x2), __float_as_int(x2), (ctrl), 0xf, 0xf, false); \
        int t3 = __builtin_amdgcn_update_dpp(__float_as_int(x3), __float_as_int(x3), (ctrl), 0xf, 0xf, false); \
        x0 = fmaxf(x0, __int_as_float(t0));                                                     \
        x1 = fmaxf(x1, __int_as_float(t1));                                                     \
        x2 = fmaxf(x2, __int_as_float(t2));                                                     \
        x3 = fmaxf(x3, __int_as_float(t3));                                                     \
    }
    DPP4(0x111)  // row_shr:1
    DPP4(0x112)  // row_shr:2
    DPP4(0x114)  // row_shr:4
    DPP4(0x118)  // row_shr:8   -> lane15 of each row16 = row max
    DPP4(0x142)  // row_bcast:15
    DPP4(0x143)  // row_bcast:31 -> lane63 = wave max
#undef DPP4
}

__global__ __launch_bounds__(256) void k_init(u64* __restrict__ keys) {
    int i = blockIdx.x * 256 + threadIdx.x;
    if (i < BB * TT) keys[i] = 0ULL;
}

// Fused pass: block = (chunk, b, t-quarter-pair z). 512 threads = 8 waves.
// Waves 0-3 cover the z-range's first 4-aligned half, waves 4-7 the second,
// over the SAME 512 anchors (2/thread). t-unroll x4.
__global__ __launch_bounds__(512) void k_phaseA(const float* __restrict__ targets,
                                                const float* __restrict__ anchors,
                                                u64* __restrict__ keys,
                                                u64* __restrict__ pa2) {
    const int b = blockIdx.y;
    const int z = blockIdx.z;
    const int tid = threadIdx.x;
    const int half = tid >> 8;            // in-block t sub-split
    const int u = tid & 255;              // pair index within chunk
    const int a0 = blockIdx.x * CHUNK + u * 2;  // AA even => pair never straddles
    const bool valid = a0 < AA;
    const int lane = tid & 63, wv = tid >> 6;   // wv 0..7; (wv&3) = lane-group within half

    __shared__ float4 sh_box[TT];                 // x1,y1,x2,y2
    __shared__ __align__(16) float sh_area[TT];   // precomputed box area
    __shared__ u64 sh_red[4][TT];                 // [wave-group][t] per-target winners
    __shared__ u64 sh_pa[CHUNK];                  // per-anchor half-0 results for merge

    if (tid < TT) {
        const float* tg = targets + ((size_t)b * TT + tid) * 5;
        float x1 = tg[0], y1 = tg[1], x2 = tg[2], y2 = tg[3];
        sh_box[tid] = make_float4(x1, y1, x2, y2);
        sh_area[tid] = __fmul_rn(__fsub_rn(x2, x1), __fsub_rn(y2, y1));
    }
    __syncthreads();

    // Anchor point-form. OOB lanes use dummy (0,0,0,0,area=1): intersection
    // is exactly 0 => IoU = 0/(areab+1) = 0 exactly; never wins reductions.
    float ax10 = 0.f, ay10 = 0.f, ax20 = 0.f, ay20 = 0.f, aa0 = 1.f;
    float ax11 = 0.f, ay11 = 0.f, ax21 = 0.f, ay21 = 0.f, aa1 = 1.f;
    if (valid) {
        const float4* anc = (const float4*)(anchors + (size_t)a0 * 4);
        float4 c0 = anc[0], c1 = anc[1];
        float hx0 = __fmul_rn(c0.z, 0.5f), hy0 = __fmul_rn(c0.w, 0.5f);
        ax10 = __fsub_rn(c0.x, hx0); ay10 = __fsub_rn(c0.y, hy0);
        ax20 = __fadd_rn(c0.x, hx0); ay20 = __fadd_rn(c0.y, hy0);
        aa0 = __fmul_rn(__fsub_rn(ax20, ax10), __fsub_rn(ay20, ay10));
        float hx1 = __fmul_rn(c1.z, 0.5f), hy1 = __fmul_rn(c1.w, 0.5f);
        ax11 = __fsub_rn(c1.x, hx1); ay11 = __fsub_rn(c1.y, hy1);
        ax21 = __fadd_rn(c1.x, hx1); ay21 = __fadd_rn(c1.y, hy1);
        aa1 = __fmul_rn(__fsub_rn(ax21, ax11), __fsub_rn(ay21, ay11));
    }

    float best0 = -1.f, best1 = -1.f;     // iou >= 0 > -1: always replaced on first t
    int gi0 = 0, gi1 = 0;
    const u32 wave_base = (u32)blockIdx.x * CHUNK + (u32)(wv & 3) * 128u;

    const int tbeg = c_tbl[z * 2 + half];
    const int tend = c_tbl[z * 2 + half + 1];
    for (int t = tbeg; t < tend; t += 4) {
        // 4 boxes + areas: reads batch under one lgkm wait; broadcast (conflict-free)
        float4 B0 = sh_box[t + 0], B1 = sh_box[t + 1];
        float4 B2 = sh_box[t + 2], B3 = sh_box[t + 3];
        const float4 arv = *(const float4*)&sh_area[t];   // t%4==0 => 16B aligned
        float ar0 = arv.x, ar1 = arv.y, ar2 = arv.z, ar3 = arv.w;

        // 8 independent IoUs: Markstein divs pipeline freely (no VCC)
        float v00 = iou_f(B0.x, B0.y, B0.z, B0.w, ar0, ax10, ay10, ax20, ay20, aa0);
        float v01 = iou_f(B0.x, B0.y, B0.z, B0.w, ar0, ax11, ay11, ax21, ay21, aa1);
        float v10 = iou_f(B1.x, B1.y, B1.z, B1.w, ar1, ax10, ay10, ax20, ay20, aa0);
        float v11 = iou_f(B1.x, B1.y, B1.z, B1.w, ar1, ax11, ay11, ax21, ay21, aa1);
        float v20 = iou_f(B2.x, B2.y, B2.z, B2.w, ar2, ax10, ay10, ax20, ay20, aa0);
        float v21 = iou_f(B2.x, B2.y, B2.z, B2.w, ar2, ax11, ay11, ax21, ay21, aa1);
        float v30 = iou_f(B3.x, B3.y, B3.z, B3.w, ar3, ax10, ay10, ax20, ay20, aa0);
        float v31 = iou_f(B3.x, B3.y, B3.z, B3.w, ar3, ax11, ay11, ax21, ay21, aa1);

        // per-anchor argmax over t: ascending t, strict > => first-t-wins
        if (v00 > best0) { best0 = v00; gi0 = t; }
        if (v10 > best0) { best0 = v10; gi0 = t + 1; }
        if (v20 > best0) { best0 = v20; gi0 = t + 2; }
        if (v30 > best0) { best0 = v30; gi0 = t + 3; }
        if (v01 > best1) { best1 = v01; gi1 = t; }
        if (v11 > best1) { best1 = v11; gi1 = t + 1; }
        if (v21 > best1) { best1 = v21; gi1 = t + 2; }
        if (v31 > best1) { best1 = v31; gi1 = t + 3; }

        // per-t argmax over this wave's 128 anchors
        float vm0 = fmaxf(v00, v01), vm1 = fmaxf(v10, v11);
        float vm2 = fmaxf(v20, v21), vm3 = fmaxf(v30, v31);
        float w0 = vm0, w1 = vm1, w2 = vm2, w3 = vm3;
        wave_max63_x4(w0, w1, w2, w3);
        u32 wm0 = (u32)__builtin_amdgcn_readlane(__float_as_int(w0), 63);
        u32 wm1 = (u32)__builtin_amdgcn_readlane(__float_as_int(w1), 63);
        u32 wm2 = (u32)__builtin_amdgcn_readlane(__float_as_int(w2), 63);
        u32 wm3 = (u32)__builtin_amdgcn_readlane(__float_as_int(w3), 63);
        // winner lane = smallest lane matching max (first-anchor-wins);
        // pair-bit from the v1>v0 ballot (strict >: first-index-wins in pair)
        u64 me0 = __ballot(vm0 == __uint_as_float(wm0));
        u64 mp0 = __ballot(v01 > v00);
        u64 me1 = __ballot(vm1 == __uint_as_float(wm1));
        u64 mp1 = __ballot(v11 > v10);
        u64 me2 = __ballot(vm2 == __uint_as_float(wm2));
        u64 mp2 = __ballot(v21 > v20);
        u64 me3 = __ballot(vm3 == __uint_as_float(wm3));
        u64 mp3 = __ballot(v31 > v30);
        u32 wl0 = (u32)(__ffsll((long long)me0) - 1);
        u32 wl1 = (u32)(__ffsll((long long)me1) - 1);
        u32 wl2 = (u32)(__ffsll((long long)me2) - 1);
        u32 wl3 = (u32)(__ffsll((long long)me3) - 1);
        u32 g0 = wave_base + wl0 * 2u + (u32)((mp0 >> wl0) & 1ULL);
        u32 g1 = wave_base + wl1 * 2u + (u32)((mp1 >> wl1) & 1ULL);
        u32 g2 = wave_base + wl2 * 2u + (u32)((mp2 >> wl2) & 1ULL);
        u32 g3 = wave_base + wl3 * 2u + (u32)((mp3 >> wl3) & 1ULL);
        if (lane == 0) {
            // [wv&3][t..t+3] contiguous => compiler can merge to b128 stores
            u64* r = &sh_red[wv & 3][t];
            r[0] = (((u64)wm0) << 32) | (u32)~g0;
            r[1] = (((u64)wm1) << 32) | (u32)~g1;
            r[2] = (((u64)wm2) << 32) | (u32)~g2;
            r[3] = (((u64)wm3) << 32) | (u32)~g3;
        }
    }
    __syncthreads();   // sh_red complete (each t written by exactly its half's 4 waves)

    // per-(b,t) winner for this block's z-range only (other rows are garbage)
    if (tid >= c_tbl[z * 2] && tid < c_tbl[z * 2 + 2]) {   // tid < 100 implied
        u64 m0 = sh_red[0][tid], m1 = sh_red[1][tid];
        u64 m2 = sh_red[2][tid], m3 = sh_red[3][tid];
        u64 m = m0 > m1 ? m0 : m1;
        if (m2 > m) m = m2;
        if (m3 > m) m = m3;
        atomicMax(&keys[b * TT + tid], m);
    }

    // Per-anchor merge across the in-block t-halves, then plain-store this
    // z's u64 key into pa2[b][a][z] (aliased onto out's loc region; k_encode
    // merges the two z keys). Key = bits<<32 | ~gi: value-desc, tie ->
    // larger ~gi = smaller gi = first-t — same semantics at every level.
    if (half == 0) {
        sh_pa[u * 2 + 0] = (((u64)__float_as_uint(best0)) << 32) | (u32)(~(u32)gi0);
        sh_pa[u * 2 + 1] = (((u64)__float_as_uint(best1)) << 32) | (u32)(~(u32)gi1);
    }
    __syncthreads();
    if (half == 1 && valid) {
        u64 k0 = (((u64)__float_as_uint(best0)) << 32) | (u32)(~(u32)gi0);
        u64 k1 = (((u64)__float_as_uint(best1)) << 32) | (u32)(~(u32)gi1);
        u64 m0 = sh_pa[u * 2 + 0]; if (k0 > m0) m0 = k0;
        u64 m1 = sh_pa[u * 2 + 1]; if (k1 > m1) m1 = k1;
        pa2[((size_t)b * AA + a0) * 2 + z] = m0;
        pa2[((size_t)b * AA + a0 + 1) * 2 + z] = m1;
    }
}

// Encode: thread per (b,a). Reads its own pa2 cell (the 16B it will then
// overwrite with loc) — read-before-write within thread, no cross-thread
// aliasing. pa2/out intentionally NOT __restrict__ (they alias).
__global__ __launch_bounds__(256) void k_encode(const float* __restrict__ targets,
                                                const float* __restrict__ anchors,
                                                const u64* __restrict__ keys,
                                                const u64* pa2,
                                                float* out) {
    const int b = blockIdx.y;
    const int a = blockIdx.x * 256 + threadIdx.x;

    __shared__ float sh_t[TT][6];   // x1,y1,x2,y2,label
    __shared__ u32 sh_ov[256];

    sh_ov[threadIdx.x] = 0;
    __syncthreads();
    for (int t = threadIdx.x; t < TT; t += 256) {
        const float* tg = targets + ((size_t)b * TT + t) * 5;
        sh_t[t][0] = tg[0]; sh_t[t][1] = tg[1];
        sh_t[t][2] = tg[2]; sh_t[t][3] = tg[3];
        sh_t[t][4] = tg[4];
        u32 at = ~(u32)(keys[b * TT + t] & 0xFFFFFFFFu);
        if ((at >> 8) == (u32)blockIdx.x)
            atomicMax(&sh_ov[at & 255], 0x100u | (u32)t);
    }
    __syncthreads();
    if (a >= AA) return;

    // merge the two z keys (contiguous 16B = this thread's own loc cell)
    const u64* pc = pa2 + ((size_t)b * AA + a) * 2;
    u64 kz0 = pc[0], kz1 = pc[1];
    u64 m = kz0 > kz1 ? kz0 : kz1;

    u32 ov = sh_ov[threadIdx.x];
    int gi; bool pos;
    if (ov) { gi = (int)(ov & 0x7F); pos = true; }
    else {
        gi = (int)((~(u32)m) & 0x7F);
        pos = __uint_as_float((u32)(m >> 32)) >= 0.5f;
    }

    const float4 anc = *(const float4*)(anchors + (size_t)a * 4);
    const float mx1 = sh_t[gi][0], my1 = sh_t[gi][1], mx2 = sh_t[gi][2], my2 = sh_t[gi][3];
    const float cx = (mx1 + mx2) * 0.5f, cy = (my1 + my2) * 0.5f;
    const float w = mx2 - mx1, h = my2 - my1;
    const float l0 = (cx - anc.x) / (0.1f * anc.z);
    const float l1 = (cy - anc.y) / (0.1f * anc.w);
    const float l2 = logf(w / anc.z) / 0.2f;
    const float l3 = logf(h / anc.w) / 0.2f;

    const size_t base = ((size_t)b * AA + a) * 4;
    *(float4*)(out + base) = make_float4(l0, l1, l2, l3);
    float conf = pos ? (float)(int)(sh_t[gi][4] + 1.0f) : 0.0f;
    out[(size_t)BB * AA * 4 + (size_t)b * AA + a] = conf;
}

extern "C" void kernel_launch(void* const* d_in, const int* in_sizes, int n_in,
                              void* d_out, int out_size, void* d_ws, size_t ws_size,
                              hipStream_t stream) {
    const float* targets = (const float*)d_in[0];  // (B,T,5)
    const float* anchors = (const float*)d_in[1];  // (A,4)
    float* out = (float*)d_out;
    u64* keys = (u64*)d_ws;                        // 51.2 KB
    u64* pa2 = (u64*)d_out;                        // aliases loc region: B*A*16B exactly

    k_init<<<(BB * TT + 255) / 256, 256, 0, stream>>>(keys);
    dim3 gA(NCHUNK, BB, 2);
    k_phaseA<<<gA, 512, 0, stream>>>(targets, anchors, keys, pa2);
    dim3 gE((AA + 255) / 256, BB);
    k_encode<<<gE, 256, 0, stream>>>(targets, anchors, keys, pa2, out);
}

// Round 6
// 109.732 us; speedup vs baseline: 4.8933x; 1.1091x over previous
//
#include <hip/hip_runtime.h>

// MultiboxLoss anchor matching: B=64, T=100, A=8732, NUM_CLASSES=21
// out = [loc (B,A,4) f32][conf (B,A) as f32]
// Round 10: fused-DPP reduction. R9 counters: VALUBusy 85%, Occupancy 67%
// -> issue-bound again; busy-work ~53us is the target. Biggest reducible
// block: the wave max-reduce, 24 stages x (v_mov_b32_dpp + v_max_f32) = 48
// insts/iter because __builtin_amdgcn_update_dpp can't fuse. VOP2 takes
// DPP on src0 directly: one v_max_f32 dst, dst_dpp, dst per stage = 24
// insts/iter (-11% issue) + removes DPP hazard pressure (4-chain
// interleave gives 3-inst spacing; s_nop 1 guards entry, s_nop 0 exit).
// bound_ctrl off => invalid lanes keep dest = max-identity: bit-identical.
//   ws: [0, 51200): u64 keys[B*T] — (iou_bits<<32)|~anchor, atomicMax
//   out loc region doubles as pa2[B][A][2] u64 scratch until k_encode.
#define BB 64
#define TT 100
#define AA 8732
#define CHUNK 512                         // anchors per block (256 thr-pairs x 2)
#define NCHUNK ((AA + CHUNK - 1) / CHUNK) // 18

typedef unsigned long long u64;
typedef unsigned int u32;
typedef unsigned short u16;

// t-range boundaries: [tbl[2z+half], tbl[2z+half+1]) per (z, in-block half).
// All multiples of 4 => clean 4-unroll, no tail code. z covers tbl[2z,2z+2).
__constant__ int c_tbl[5] = {0, 28, 52, 76, 100};

// Faithful (<=1ulp) f32 division, 5 VALU, no VCC. Inputs always normal
// (u >= 4e-4); i == 0 returns exactly 0. Markstein remainder correction.
__device__ __forceinline__ float fdiv_faithful(float i, float u) {
    float r = __builtin_amdgcn_rcpf(u);                     // v_rcp_f32
    r = __builtin_fmaf(__builtin_fmaf(-u, r, 1.0f), r, r);  // Newton
    float q = __fmul_rn(i, r);
    float rem = __builtin_fmaf(-u, q, i);                   // exact remainder
    return __builtin_fmaf(rem, r, q);
}

// Bit-matching (vs numpy f32) intersection/union: _rn blocks fp-contract.
__device__ __forceinline__ float iou_f(float bx1, float by1, float bx2, float by2, float areab,
                                       float ax1, float ay1, float ax2, float ay2, float areaa) {
    float dx = fmaxf(__fsub_rn(fminf(bx2, ax2), fmaxf(bx1, ax1)), 0.0f);
    float dy = fmaxf(__fsub_rn(fminf(by2, ay2), fmaxf(by1, ay1)), 0.0f);
    float inter = __fmul_rn(dx, dy);
    float uni = __fsub_rn(__fadd_rn(areab, areaa), inter);
    return fdiv_faithful(inter, uni);
}

// 4 interleaved wave64 max reductions, DPP fused into v_max_f32 (1 inst
// per stage per chain). Lane 63 of each holds the wave max. Chain i stage
// k reads its own stage k-1 result 4 insts earlier => DPP
// read-after-VALU-write (2 wait states) satisfied without s_nops.
// s_nop 1: guard vs the compiler's pair-max writes immediately before.
// s_nop 0: guard the compiler's readlane immediately after (it can't see
// hazards inside this block). bound_ctrl off: invalid lanes keep dest
// (= running max) — exact same semantics as the update_dpp version.
__device__ __forceinline__ void wave_max63_x4(float& x0, float& x1, float& x2, float& x3) {
    asm volatile(
        "s_nop 1\n\t"
        "v_max_f32 %0, %0, %0 row_shr:1\n\t"
        "v_max_f32 %1, %1, %1 row_shr:1\n\t"
        "v_max_f32 %2, %2, %2 row_shr:1\n\t"
        "v_max_f32 %3, %3, %3 row_shr:1\n\t"
        "v_max_f32 %0, %0, %0 row_shr:2\n\t"
        "v_max_f32 %1, %1, %1 row_shr:2\n\t"
        "v_max_f32 %2, %2, %2 row_shr:2\n\t"
        "v_max_f32 %3, %3, %3 row_shr:2\n\t"
        "v_max_f32 %0, %0, %0 row_shr:4\n\t"
        "v_max_f32 %1, %1, %1 row_shr:4\n\t"
        "v_max_f32 %2, %2, %2 row_shr:4\n\t"
        "v_max_f32 %3, %3, %3 row_shr:4\n\t"
        "v_max_f32 %0, %0, %0 row_shr:8\n\t"
        "v_max_f32 %1, %1, %1 row_shr:8\n\t"
        "v_max_f32 %2, %2, %2 row_shr:8\n\t"
        "v_max_f32 %3, %3, %3 row_shr:8\n\t"
        "v_max_f32 %0, %0, %0 row_bcast:15\n\t"
        "v_max_f32 %1, %1, %1 row_bcast:15\n\t"
        "v_max_f32 %2, %2, %2 row_bcast:15\n\t"
        "v_max_f32 %3, %3, %3 row_bcast:15\n\t"
        "v_max_f32 %0, %0, %0 row_bcast:31\n\t"
        "v_max_f32 %1, %1, %1 row_bcast:31\n\t"
        "v_max_f32 %2, %2, %2 row_bcast:31\n\t"
        "v_max_f32 %3, %3, %3 row_bcast:31\n\t"
        "s_nop 0"
        : "+v"(x0), "+v"(x1), "+v"(x2), "+v"(x3));
}

__global__ __launch_bounds__(256) void k_init(u64* __restrict__ keys) {
    int i = blockIdx.x * 256 + threadIdx.x;
    if (i < BB * TT) keys[i] = 0ULL;
}

// Fused pass: block = (chunk, b, t-quarter-pair z). 512 threads = 8 waves.
// Waves 0-3 cover the z-range's first 4-aligned half, waves 4-7 the second,
// over the SAME 512 anchors (2/thread). t-unroll x4.
__global__ __launch_bounds__(512) void k_phaseA(const float* __restrict__ targets,
                                                const float* __restrict__ anchors,
                                                u64* __restrict__ keys,
                                                u64* __restrict__ pa2) {
    const int b = blockIdx.y;
    const int z = blockIdx.z;
    const int tid = threadIdx.x;
    const int half = tid >> 8;            // in-block t sub-split
    const int u = tid & 255;              // pair index within chunk
    const int a0 = blockIdx.x * CHUNK + u * 2;  // AA even => pair never straddles
    const bool valid = a0 < AA;
    const int lane = tid & 63, wv = tid >> 6;   // wv 0..7; (wv&3) = lane-group within half

    __shared__ float4 sh_box[TT];                 // x1,y1,x2,y2
    __shared__ __align__(16) float sh_area[TT];   // precomputed box area
    __shared__ u64 sh_red[4][TT];                 // [wave-group][t] per-target winners
    __shared__ u64 sh_pa[CHUNK];                  // per-anchor half-0 results for merge

    if (tid < TT) {
        const float* tg = targets + ((size_t)b * TT + tid) * 5;
        float x1 = tg[0], y1 = tg[1], x2 = tg[2], y2 = tg[3];
        sh_box[tid] = make_float4(x1, y1, x2, y2);
        sh_area[tid] = __fmul_rn(__fsub_rn(x2, x1), __fsub_rn(y2, y1));
    }
    __syncthreads();

    // Anchor point-form. OOB lanes use dummy (0,0,0,0,area=1): intersection
    // is exactly 0 => IoU = 0/(areab+1) = 0 exactly; never wins reductions.
    float ax10 = 0.f, ay10 = 0.f, ax20 = 0.f, ay20 = 0.f, aa0 = 1.f;
    float ax11 = 0.f, ay11 = 0.f, ax21 = 0.f, ay21 = 0.f, aa1 = 1.f;
    if (valid) {
        const float4* anc = (const float4*)(anchors + (size_t)a0 * 4);
        float4 c0 = anc[0], c1 = anc[1];
        float hx0 = __fmul_rn(c0.z, 0.5f), hy0 = __fmul_rn(c0.w, 0.5f);
        ax10 = __fsub_rn(c0.x, hx0); ay10 = __fsub_rn(c0.y, hy0);
        ax20 = __fadd_rn(c0.x, hx0); ay20 = __fadd_rn(c0.y, hy0);
        aa0 = __fmul_rn(__fsub_rn(ax20, ax10), __fsub_rn(ay20, ay10));
        float hx1 = __fmul_rn(c1.z, 0.5f), hy1 = __fmul_rn(c1.w, 0.5f);
        ax11 = __fsub_rn(c1.x, hx1); ay11 = __fsub_rn(c1.y, hy1);
        ax21 = __fadd_rn(c1.x, hx1); ay21 = __fadd_rn(c1.y, hy1);
        aa1 = __fmul_rn(__fsub_rn(ax21, ax11), __fsub_rn(ay21, ay11));
    }

    float best0 = -1.f, best1 = -1.f;     // iou >= 0 > -1: always replaced on first t
    int gi0 = 0, gi1 = 0;
    const u32 wave_base = (u32)blockIdx.x * CHUNK + (u32)(wv & 3) * 128u;

    const int tbeg = c_tbl[z * 2 + half];
    const int tend = c_tbl[z * 2 + half + 1];
    for (int t = tbeg; t < tend; t += 4) {
        // 4 boxes + areas: reads batch under one lgkm wait; broadcast (conflict-free)
        float4 B0 = sh_box[t + 0], B1 = sh_box[t + 1];
        float4 B2 = sh_box[t + 2], B3 = sh_box[t + 3];
        const float4 arv = *(const float4*)&sh_area[t];   // t%4==0 => 16B aligned
        float ar0 = arv.x, ar1 = arv.y, ar2 = arv.z, ar3 = arv.w;

        // 8 independent IoUs: Markstein divs pipeline freely (no VCC)
        float v00 = iou_f(B0.x, B0.y, B0.z, B0.w, ar0, ax10, ay10, ax20, ay20, aa0);
        float v01 = iou_f(B0.x, B0.y, B0.z, B0.w, ar0, ax11, ay11, ax21, ay21, aa1);
        float v10 = iou_f(B1.x, B1.y, B1.z, B1.w, ar1, ax10, ay10, ax20, ay20, aa0);
        float v11 = iou_f(B1.x, B1.y, B1.z, B1.w, ar1, ax11, ay11, ax21, ay21, aa1);
        float v20 = iou_f(B2.x, B2.y, B2.z, B2.w, ar2, ax10, ay10, ax20, ay20, aa0);
        float v21 = iou_f(B2.x, B2.y, B2.z, B2.w, ar2, ax11, ay11, ax21, ay21, aa1);
        float v30 = iou_f(B3.x, B3.y, B3.z, B3.w, ar3, ax10, ay10, ax20, ay20, aa0);
        float v31 = iou_f(B3.x, B3.y, B3.z, B3.w, ar3, ax11, ay11, ax21, ay21, aa1);

        // per-anchor argmax over t: ascending t, strict > => first-t-wins
        if (v00 > best0) { best0 = v00; gi0 = t; }
        if (v10 > best0) { best0 = v10; gi0 = t + 1; }
        if (v20 > best0) { best0 = v20; gi0 = t + 2; }
        if (v30 > best0) { best0 = v30; gi0 = t + 3; }
        if (v01 > best1) { best1 = v01; gi1 = t; }
        if (v11 > best1) { best1 = v11; gi1 = t + 1; }
        if (v21 > best1) { best1 = v21; gi1 = t + 2; }
        if (v31 > best1) { best1 = v31; gi1 = t + 3; }

        // per-t argmax over this wave's 128 anchors
        float vm0 = fmaxf(v00, v01), vm1 = fmaxf(v10, v11);
        float vm2 = fmaxf(v20, v21), vm3 = fmaxf(v30, v31);
        float w0 = vm0, w1 = vm1, w2 = vm2, w3 = vm3;
        wave_max63_x4(w0, w1, w2, w3);
        u32 wm0 = (u32)__builtin_amdgcn_readlane(__float_as_int(w0), 63);
        u32 wm1 = (u32)__builtin_amdgcn_readlane(__float_as_int(w1), 63);
        u32 wm2 = (u32)__builtin_amdgcn_readlane(__float_as_int(w2), 63);
        u32 wm3 = (u32)__builtin_amdgcn_readlane(__float_as_int(w3), 63);
        // winner lane = smallest lane matching max (first-anchor-wins);
        // pair-bit from the v1>v0 ballot (strict >: first-index-wins in pair)
        u64 me0 = __ballot(vm0 == __uint_as_float(wm0));
        u64 mp0 = __ballot(v01 > v00);
        u64 me1 = __ballot(vm1 == __uint_as_float(wm1));
        u64 mp1 = __ballot(v11 > v10);
        u64 me2 = __ballot(vm2 == __uint_as_float(wm2));
        u64 mp2 = __ballot(v21 > v20);
        u64 me3 = __ballot(vm3 == __uint_as_float(wm3));
        u64 mp3 = __ballot(v31 > v30);
        u32 wl0 = (u32)(__ffsll((long long)me0) - 1);
        u32 wl1 = (u32)(__ffsll((long long)me1) - 1);
        u32 wl2 = (u32)(__ffsll((long long)me2) - 1);
        u32 wl3 = (u32)(__ffsll((long long)me3) - 1);
        u32 g0 = wave_base + wl0 * 2u + (u32)((mp0 >> wl0) & 1ULL);
        u32 g1 = wave_base + wl1 * 2u + (u32)((mp1 >> wl1) & 1ULL);
        u32 g2 = wave_base + wl2 * 2u + (u32)((mp2 >> wl2) & 1ULL);
        u32 g3 = wave_base + wl3 * 2u + (u32)((mp3 >> wl3) & 1ULL);
        if (lane == 0) {
            // [wv&3][t..t+3] contiguous => compiler can merge to b128 stores
            u64* r = &sh_red[wv & 3][t];
            r[0] = (((u64)wm0) << 32) | (u32)~g0;
            r[1] = (((u64)wm1) << 32) | (u32)~g1;
            r[2] = (((u64)wm2) << 32) | (u32)~g2;
            r[3] = (((u64)wm3) << 32) | (u32)~g3;
        }
    }
    __syncthreads();   // sh_red complete (each t written by exactly its half's 4 waves)

    // per-(b,t) winner for this block's z-range only (other rows are garbage)
    if (tid >= c_tbl[z * 2] && tid < c_tbl[z * 2 + 2]) {   // tid < 100 implied
        u64 m0 = sh_red[0][tid], m1 = sh_red[1][tid];
        u64 m2 = sh_red[2][tid], m3 = sh_red[3][tid];
        u64 m = m0 > m1 ? m0 : m1;
        if (m2 > m) m = m2;
        if (m3 > m) m = m3;
        atomicMax(&keys[b * TT + tid], m);
    }

    // Per-anchor merge across the in-block t-halves, then plain-store this
    // z's u64 key into pa2[b][a][z] (aliased onto out's loc region; k_encode
    // merges the two z keys). Key = bits<<32 | ~gi: value-desc, tie ->
    // larger ~gi = smaller gi = first-t — same semantics at every level.
    if (half == 0) {
        sh_pa[u * 2 + 0] = (((u64)__float_as_uint(best0)) << 32) | (u32)(~(u32)gi0);
        sh_pa[u * 2 + 1] = (((u64)__float_as_uint(best1)) << 32) | (u32)(~(u32)gi1);
    }
    __syncthreads();
    if (half == 1 && valid) {
        u64 k0 = (((u64)__float_as_uint(best0)) << 32) | (u32)(~(u32)gi0);
        u64 k1 = (((u64)__float_as_uint(best1)) << 32) | (u32)(~(u32)gi1);
        u64 m0 = sh_pa[u * 2 + 0]; if (k0 > m0) m0 = k0;
        u64 m1 = sh_pa[u * 2 + 1]; if (k1 > m1) m1 = k1;
        pa2[((size_t)b * AA + a0) * 2 + z] = m0;
        pa2[((size_t)b * AA + a0 + 1) * 2 + z] = m1;
    }
}

// Encode: thread per (b,a). Reads its own pa2 cell (the 16B it will then
// overwrite with loc) — read-before-write within thread, no cross-thread
// aliasing. pa2/out intentionally NOT __restrict__ (they alias).
__global__ __launch_bounds__(256) void k_encode(const float* __restrict__ targets,
                                                const float* __restrict__ anchors,
                                                const u64* __restrict__ keys,
                                                const u64* pa2,
                                                float* out) {
    const int b = blockIdx.y;
    const int a = blockIdx.x * 256 + threadIdx.x;

    __shared__ float sh_t[TT][6];   // x1,y1,x2,y2,label
    __shared__ u32 sh_ov[256];

    sh_ov[threadIdx.x] = 0;
    __syncthreads();
    for (int t = threadIdx.x; t < TT; t += 256) {
        const float* tg = targets + ((size_t)b * TT + t) * 5;
        sh_t[t][0] = tg[0]; sh_t[t][1] = tg[1];
        sh_t[t][2] = tg[2]; sh_t[t][3] = tg[3];
        sh_t[t][4] = tg[4];
        u32 at = ~(u32)(keys[b * TT + t] & 0xFFFFFFFFu);
        if ((at >> 8) == (u32)blockIdx.x)
            atomicMax(&sh_ov[at & 255], 0x100u | (u32)t);
    }
    __syncthreads();
    if (a >= AA) return;

    // merge the two z keys (contiguous 16B = this thread's own loc cell)
    const u64* pc = pa2 + ((size_t)b * AA + a) * 2;
    u64 kz0 = pc[0], kz1 = pc[1];
    u64 m = kz0 > kz1 ? kz0 : kz1;

    u32 ov = sh_ov[threadIdx.x];
    int gi; bool pos;
    if (ov) { gi = (int)(ov & 0x7F); pos = true; }
    else {
        gi = (int)((~(u32)m) & 0x7F);
        pos = __uint_as_float((u32)(m >> 32)) >= 0.5f;
    }

    const float4 anc = *(const float4*)(anchors + (size_t)a * 4);
    const float mx1 = sh_t[gi][0], my1 = sh_t[gi][1], mx2 = sh_t[gi][2], my2 = sh_t[gi][3];
    const float cx = (mx1 + mx2) * 0.5f, cy = (my1 + my2) * 0.5f;
    const float w = mx2 - mx1, h = my2 - my1;
    const float l0 = (cx - anc.x) / (0.1f * anc.z);
    const float l1 = (cy - anc.y) / (0.1f * anc.w);
    const float l2 = logf(w / anc.z) / 0.2f;
    const float l3 = logf(h / anc.w) / 0.2f;

    const size_t base = ((size_t)b * AA + a) * 4;
    *(float4*)(out + base) = make_float4(l0, l1, l2, l3);
    float conf = pos ? (float)(int)(sh_t[gi][4] + 1.0f) : 0.0f;
    out[(size_t)BB * AA * 4 + (size_t)b * AA + a] = conf;
}

extern "C" void kernel_launch(void* const* d_in, const int* in_sizes, int n_in,
                              void* d_out, int out_size, void* d_ws, size_t ws_size,
                              hipStream_t stream) {
    const float* targets = (const float*)d_in[0];  // (B,T,5)
    const float* anchors = (const float*)d_in[1];  // (A,4)
    float* out = (float*)d_out;
    u64* keys = (u64*)d_ws;                        // 51.2 KB
    u64* pa2 = (u64*)d_out;                        // aliases loc region: B*A*16B exactly

    k_init<<<(BB * TT + 255) / 256, 256, 0, stream>>>(keys);
    dim3 gA(NCHUNK, BB, 2);
    k_phaseA<<<gA, 512, 0, stream>>>(targets, anchors, keys, pa2);
    dim3 gE((AA + 255) / 256, BB);
    k_encode<<<gE, 256, 0, stream>>>(targets, anchors, keys, pa2, out);
}